// Round 6
// baseline (164.961 us; speedup 1.0000x reference)
//
#include <hip/hip_runtime.h>

#define DEV static __device__ __forceinline__

typedef short s16;
typedef __attribute__((ext_vector_type(4))) short short4_t;
typedef __attribute__((ext_vector_type(8))) short short8;
typedef __attribute__((ext_vector_type(4))) float f32x4;

#define NB 2
#define NH 8
#define SL 2048
#define DM 512
#define DH 64
#define NTOP 7
#define LOG2E 1.4426950408889634f
#define NROWS (NB*NH*SL)      // 32768
#define FSPLIT 2
#define SSPLIT 2

DEV short f2bf(float x){
  union { float f; unsigned u; } v; v.f = x;
  unsigned r = v.u + 0x7fffu + ((v.u >> 16) & 1u);
  return (short)(r >> 16);
}
DEV float bf2f(short b){
  union { float f; unsigned u; } v; v.u = ((unsigned)(unsigned short)b) << 16;
  return v.f;
}
DEV f32x4 mfma16(short8 a, short8 b, f32x4 c){
  return __builtin_amdgcn_mfma_f32_16x16x32_bf16(a, b, c, 0, 0, 0);
}
DEV unsigned cvtpk(float lo, float hi){
  unsigned r;
  asm("v_cvt_pk_bf16_f32 %0, %1, %2" : "=v"(r) : "v"(lo), "v"(hi));
  return r;
}
// async global->LDS, 16B per lane; LDS dest = wave-uniform base + lane*16
DEV void gl2lds16(const s16* g, s16* l){
  __builtin_amdgcn_global_load_lds(
      (const __attribute__((address_space(1))) unsigned*)g,
      (__attribute__((address_space(3))) unsigned*)l, 16, 0, 0);
}

// ---------- fused prep: converts + tiled khatT transpose ----------
__global__ void prep_kernel(const float* __restrict__ query, const float* __restrict__ key,
    const float* __restrict__ value,
    const float* __restrict__ wq, const float* __restrict__ wk,
    const float* __restrict__ wv, const float* __restrict__ wo,
    s16* __restrict__ q_hi, s16* __restrict__ q_lo, s16* __restrict__ xk, s16* __restrict__ xv,
    s16* __restrict__ khi, s16* __restrict__ klo,
    s16* __restrict__ wqb, s16* __restrict__ wkb, s16* __restrict__ wvb, s16* __restrict__ wob){
  const int nbb = (NB*SL*DM)/256;   // 8192
  const int wbb = (DM*DM)/256;      // 1024
  __shared__ s16 thi[64][66];
  __shared__ s16 tlo[64][66];
  int bid = blockIdx.x;
  int t = threadIdx.x;
  if (bid < nbb){
    int i = bid*256 + t;
    float v = query[i];
    short h = f2bf(v);
    q_hi[i] = h;
    q_lo[i] = f2bf(v - bf2f(h));
    return;
  }
  bid -= nbb;
  if (bid < nbb){ int i = bid*256 + t; xk[i] = f2bf(key[i]); return; }
  bid -= nbb;
  if (bid < nbb){ int i = bid*256 + t; xv[i] = f2bf(value[i]); return; }
  bid -= nbb;
  if (bid < 512){
    // khatT[b][h][k][d] = key[b, d*32 + k/64, h*64 + k%64], tiled (b,h,k6)
    int k6 = bid & 31, h = (bid >> 5) & 7, b = bid >> 8;
    int kl = t & 63, dq = t >> 6;
    #pragma unroll
    for (int dd = 0; dd < 16; ++dd){
      int d = dd*4 + dq;
      float v = key[((size_t)b*SL + d*32 + k6)*DM + h*DH + kl];
      short hh = f2bf(v);
      thi[d][kl] = hh;
      tlo[d][kl] = f2bf(v - bf2f(hh));
    }
    __syncthreads();
    int d2 = t & 63, kq = t >> 6;
    size_t obase = (((size_t)(b*NH + h))*SL + (size_t)k6*64)*DH;
    #pragma unroll
    for (int kk = 0; kk < 16; ++kk){
      int kl2 = kk*4 + kq;
      khi[obase + (size_t)kl2*DH + d2] = thi[d2][kl2];
      klo[obase + (size_t)kl2*DH + d2] = tlo[d2][kl2];
    }
    return;
  }
  bid -= 512;
  if (bid < wbb){ int i = bid*256 + t; wqb[i] = f2bf(wq[i]); return; }
  bid -= wbb;
  if (bid < wbb){ int i = bid*256 + t; wkb[i] = f2bf(wk[i]); return; }
  bid -= wbb;
  if (bid < wbb){ int i = bid*256 + t; wvb[i] = f2bf(wv[i]); return; }
  bid -= wbb;
  if (bid < wbb){ int i = bid*256 + t; wob[i] = f2bf(wo[i]); return; }
}

// ---------- tiled transpose: VpT[b][h][d][k] = Vp[b][k][h*64+d] ----------
__global__ __launch_bounds__(256) void vpt_kernel(const s16* __restrict__ Vp, s16* __restrict__ VpT){
  __shared__ s16 tl[64][66];
  int bid = blockIdx.x;                 // (b,h,k6)
  int k6 = bid & 31, h = (bid >> 5) & 7, b = bid >> 8;
  int t = threadIdx.x;
  int d = t & 63, kq = t >> 6;
  #pragma unroll
  for (int kk = 0; kk < 16; ++kk){
    int kl = kk*4 + kq;
    tl[kl][d] = Vp[((size_t)b*SL + k6*64 + kl)*DM + h*DH + d];
  }
  __syncthreads();
  int kl2 = t & 63, dq = t >> 6;
  size_t obase = ((size_t)(b*NH + h))*DH*SL + (size_t)k6*64;
  #pragma unroll
  for (int dd = 0; dd < 16; ++dd){
    int d2 = dd*4 + dq;
    VpT[obase + (size_t)d2*SL + kl2] = tl[kl2][d2];
  }
}

// ---------- LDS-staged GEMM: C[n][o] = (sum_k A[n][k]*Bw[o][k] + bias[o])*scale ----------
template<int OUTF32>
DEV void gemm_body(const s16* __restrict__ A, const s16* __restrict__ Bw,
        const float* __restrict__ bias, void* __restrict__ Cout, int bid, int tid, float scale){
  __shared__ __align__(16) s16 Abuf[2][128*64];
  __shared__ __align__(16) s16 Bbuf[2][64*64];
  int nt = bid >> 3, ot = bid & 7;
  int w = tid >> 6, l = tid & 63;
  int lr = l & 15, lg = l >> 4;
  int n0 = nt*128, o0 = ot*64;
  auto stage = [&](int cur, int kg){
    #pragma unroll
    for (int i = 0; i < 4; ++i){
      int r = w*32 + i*8 + (l>>3);
      int cs = (l&7) ^ (r&7);
      gl2lds16(A + (size_t)(n0 + r)*DM + kg + cs*8, &Abuf[cur][(w*32 + i*8)*64]);
    }
    #pragma unroll
    for (int i = 0; i < 2; ++i){
      int r = w*16 + i*8 + (l>>3);
      int cs = (l&7) ^ (r&7);
      gl2lds16(Bw + (size_t)(o0 + r)*DM + kg + cs*8, &Bbuf[cur][(w*16 + i*8)*64]);
    }
  };
  f32x4 acc[2][4] = {};
  stage(0, 0);
  __syncthreads();
  const int NIT = DM/64;  // 8
  for (int it = 0; it < NIT; ++it){
    int cur = it & 1;
    if (it + 1 < NIT) stage(cur^1, (it+1)*64);
    #pragma unroll
    for (int kc = 0; kc < 2; ++kc){
      short8 a0 = *(const short8*)&Abuf[cur][(w*32 +      lr)*64 + ((kc*4+lg) ^ (lr&7))*8];
      short8 a1 = *(const short8*)&Abuf[cur][(w*32 + 16 + lr)*64 + ((kc*4+lg) ^ (lr&7))*8];
      #pragma unroll
      for (int c = 0; c < 4; ++c){
        short8 bf = *(const short8*)&Bbuf[cur][(c*16 + lr)*64 + ((kc*4+lg) ^ (lr&7))*8];
        acc[0][c] = mfma16(a0, bf, acc[0][c]);
        acc[1][c] = mfma16(a1, bf, acc[1][c]);
      }
    }
    __syncthreads();
  }
  #pragma unroll
  for (int sub = 0; sub < 2; ++sub)
    #pragma unroll
    for (int c = 0; c < 4; ++c){
      int col = o0 + c*16 + lr;
      float bb = bias[col];
      #pragma unroll
      for (int j = 0; j < 4; ++j){
        int row = n0 + w*32 + sub*16 + lg*4 + j;
        float v = (acc[sub][c][j] + bb)*scale;
        if (OUTF32) ((float*)Cout)[(size_t)row*DM + col] = v;
        else        ((s16*) Cout)[(size_t)row*DM + col] = f2bf(v);
      }
    }
}

__global__ __launch_bounds__(256) void gemm_proj(const s16* __restrict__ Aq, const s16* __restrict__ Ak,
        const s16* __restrict__ Av, const s16* __restrict__ Wq, const s16* __restrict__ Wk,
        const s16* __restrict__ Wv, const float* __restrict__ bq, const float* __restrict__ bk,
        const float* __restrict__ bv, s16* __restrict__ Oq, s16* __restrict__ Ok, s16* __restrict__ Ov){
  int which = blockIdx.x >> 8;
  const s16* A  = which == 0 ? Aq : which == 1 ? Ak : Av;
  const s16* Bw = which == 0 ? Wq : which == 1 ? Wk : Wv;
  const float* bias = which == 0 ? bq : which == 1 ? bk : bv;
  s16* C = which == 0 ? Oq : which == 1 ? Ok : Ov;
  float scale = which == 0 ? 0.125f*LOG2E : 1.0f;  // fold softmax scale+log2e into Q
  gemm_body<0>(A, Bw, bias, C, blockIdx.x & 255, threadIdx.x, scale);
}

__global__ __launch_bounds__(256) void gemm_out(const s16* __restrict__ A, const s16* __restrict__ Bw,
        const float* __restrict__ bias, float* __restrict__ Cout){
  gemm_body<1>(A, Bw, bias, Cout, blockIdx.x, threadIdx.x, 1.0f);
}

// ---------- stats partials (swapped layout, LDS-staged khat, KVBLK=64, split-K x2) ----------
__global__ __launch_bounds__(256) void stats_kernel(const s16* __restrict__ qhi, const s16* __restrict__ qlo,
        const s16* __restrict__ khi, const s16* __restrict__ klo,
        float* __restrict__ Mmx, float* __restrict__ Msm){
  __shared__ __align__(16) s16 Hbuf[2][64*64];
  __shared__ __align__(16) s16 Lbuf[2][64*64];
  int bid = blockIdx.x;
  int s = bid & 1, qt = (bid >> 1) & 31, h = (bid >> 6) & 7, b = bid >> 9;
  int tid = threadIdx.x;
  int w = tid >> 6, l = tid & 63;
  int lr = l & 15, lg = l >> 4;
  int dx = lr & 7;
  int q0 = qt*64 + w*16;
  const s16* qp  = qhi + ((size_t)b*SL + q0 + lr)*DM + h*DH + lg*8;
  const s16* qlp = qlo + ((size_t)b*SL + q0 + lr)*DM + h*DH + lg*8;
  short8 qh0 = *(const short8*)qp;
  short8 qh1 = *(const short8*)(qp + 32);
  short8 ql0 = *(const short8*)qlp;
  short8 ql1 = *(const short8*)(qlp + 32);
  const s16* kb  = khi + ((size_t)b*NH + h)*SL*DH;
  const s16* klb = klo + ((size_t)b*NH + h)*SL*DH;
  auto stage = [&](int cur, int kg){
    #pragma unroll
    for (int i = 0; i < 2; ++i){
      int r = w*16 + i*8 + (l>>3);
      int cs = (l&7) ^ (r&7);
      gl2lds16(kb  + (size_t)(kg + r)*DH + cs*8, &Hbuf[cur][(w*16 + i*8)*64]);
    }
    #pragma unroll
    for (int i = 0; i < 2; ++i){
      int r = w*16 + i*8 + (l>>3);
      int cs = (l&7) ^ (r&7);
      gl2lds16(klb + (size_t)(kg + r)*DH + cs*8, &Lbuf[cur][(w*16 + i*8)*64]);
    }
  };
  float mx = -1e30f, sm = 0.f;
  int kbeg = s*(SL/SSPLIT);
  const int NIT = (SL/SSPLIT)/64;  // 16
  stage(0, kbeg);
  __syncthreads();
  for (int it = 0; it < NIT; ++it){
    int cur = it & 1;
    if (it + 1 < NIT) stage(cur^1, kbeg + (it+1)*64);
    #pragma unroll
    for (int t = 0; t < 4; ++t){
      int rb = (t*16 + lr)*64;
      short8 kh0 = *(const short8*)&Hbuf[cur][rb + ((  lg) ^ dx)*8];
      short8 kh1 = *(const short8*)&Hbuf[cur][rb + ((4+lg) ^ dx)*8];
      short8 kl0 = *(const short8*)&Lbuf[cur][rb + ((  lg) ^ dx)*8];
      short8 kl1 = *(const short8*)&Lbuf[cur][rb + ((4+lg) ^ dx)*8];
      f32x4 sacc = {};
      sacc = mfma16(kh0, qh0, sacc);
      sacc = mfma16(kh1, qh1, sacc);
      sacc = mfma16(kl0, qh0, sacc);
      sacc = mfma16(kl1, qh1, sacc);
      sacc = mfma16(kh0, ql0, sacc);
      sacc = mfma16(kh1, ql1, sacc);
      #pragma unroll
      for (int j = 0; j < 4; ++j){ mx = fmaxf(mx, sacc[j]); sm += sacc[j]; }
    }
    __syncthreads();
  }
  mx = fmaxf(mx, __shfl_xor(mx, 16));
  mx = fmaxf(mx, __shfl_xor(mx, 32));
  sm += __shfl_xor(sm, 16);
  sm += __shfl_xor(sm, 32);
  if (lg == 0){
    size_t row = ((size_t)b*NH + h)*SL + q0 + lr;
    Mmx[(size_t)s*NROWS + row] = mx;
    Msm[(size_t)s*NROWS + row] = sm;
  }
}

// ---------- top-7 per (b,h), combining split partials ----------
__global__ __launch_bounds__(64) void topk_kernel(const float* __restrict__ Mmx,
        const float* __restrict__ Msm, int* __restrict__ topidx, int* __restrict__ rowsel){
  int bh = blockIdx.x;
  int l = threadIdx.x;
  __shared__ float smv[SL];
  size_t base = (size_t)bh*SL;
  for (int i = l; i < SL; i += 64){
    float mx = Mmx[base + i];
    float sm = Msm[base + i];
    #pragma unroll
    for (int s = 1; s < SSPLIT; ++s){
      mx = fmaxf(mx, Mmx[(size_t)s*NROWS + base + i]);
      sm += Msm[(size_t)s*NROWS + base + i];
    }
    smv[i] = mx - sm*(1.0f/SL);
    rowsel[base + i] = -1;
  }
  __syncthreads();
  for (int t = 0; t < NTOP; ++t){
    float bvv = -1e38f; int bi = SL;
    for (int i = l; i < SL; i += 64){
      float v = smv[i];
      if (v > bvv){ bvv = v; bi = i; }
    }
    for (int off = 32; off >= 1; off >>= 1){
      float ov = __shfl_xor(bvv, off);
      int oi = __shfl_xor(bi, off);
      if (ov > bvv || (ov == bvv && oi < bi)){ bvv = ov; bi = oi; }
    }
    if (l == 0){
      topidx[bh*8 + t] = bi;
      rowsel[base + bi] = t;
    }
    smv[bi] = -1e38f;
    __syncthreads();
  }
}

// ---------- mask rows (exact f32, LDS-tiled over (b,h,k6)), pre-scaled by LOG2E ----------
__global__ __launch_bounds__(256) void maskrow_kernel(const float* __restrict__ query,
        const float* __restrict__ key, const int* __restrict__ topidx, float* __restrict__ maskrows){
  __shared__ float tile[64][65];      // [d][kl]
  __shared__ float qs[NTOP][64];
  int bid = blockIdx.x;               // (b,h,k6)
  int k6 = bid & 31, h = (bid >> 5) & 7, b = bid >> 8;
  int bh = b*NH + h;
  int t = threadIdx.x;
  int kl = t & 63, w = t >> 6;
  for (int i = t; i < NTOP*64; i += 256){
    int tt = i >> 6, d = i & 63;
    qs[tt][d] = query[((size_t)b*SL + topidx[bh*8 + tt])*DM + h*DH + d];
  }
  #pragma unroll
  for (int dd = 0; dd < 16; ++dd){
    int d = dd*4 + w;
    tile[d][kl] = key[((size_t)b*SL + d*32 + k6)*DM + h*DH + kl];
  }
  __syncthreads();
  for (int tt = w; tt < NTOP; tt += 4){
    float acc = 0.f;
    #pragma unroll
    for (int d = 0; d < 64; ++d)
      acc = fmaf(qs[tt][d], tile[d][kl], acc);
    maskrows[((size_t)bh*NTOP + tt)*SL + k6*64 + kl] = acc*LOG2E;
  }
}

// ---------- flash attention: swapped layout, KVBLK=64, no-max softmax, split-K x2 ----------
// softmax without max-subtraction: |S*0.125*log2e| <= ~2 unmasked; masked rows add
// |QK_red|*log2e <= ~60 << 127 -> exp2 cannot overflow f32, shift-invariance exact.
__global__ __launch_bounds__(256) void flash_kernel(const s16* __restrict__ Qp, const s16* __restrict__ Kp,
        const s16* __restrict__ VpT, const float* __restrict__ maskrows, const int* __restrict__ rowsel,
        float* __restrict__ Opart, float* __restrict__ lpart){
  __shared__ __align__(16) s16 Kbuf[2][64*64];   // [k-row][64 d], swz 16B-chunk ^= (row&7)
  __shared__ __align__(16) s16 Vbuf[2][64*64];   // [d-row][64 k], swz 8B-granule ^= (d&7)<<1
  int bid = blockIdx.x;
  int s = bid & 1, qt = (bid >> 1) & 31, h = (bid >> 6) & 7, b = bid >> 9;
  int tid = threadIdx.x;
  int w = tid >> 6, l = tid & 63;
  int lr = l & 15, lg = l >> 4;
  int dx = lr & 7;
  int q0 = qt*64 + w*16;
  int bh = b*NH + h;
  const s16* qp = Qp + ((size_t)b*SL + q0 + lr)*DM + h*DH + lg*8;
  short8 bq0 = *(const short8*)qp;
  short8 bq1 = *(const short8*)(qp + 32);
  int sel = rowsel[(size_t)bh*SL + q0 + lr];
  const float* mrow = maskrows + ((size_t)bh*NTOP + (sel >= 0 ? sel : 0))*SL;
  const s16* kpb = Kp + (size_t)b*SL*DM + h*DH;
  const s16* vtb = VpT + (size_t)bh*DH*SL;
  auto stage = [&](int cur, int kg){
    #pragma unroll
    for (int i = 0; i < 2; ++i){
      int r = w*16 + i*8 + (l>>3);
      int cs = (l&7) ^ (r&7);
      gl2lds16(kpb + (size_t)(kg + r)*DM + cs*8, &Kbuf[cur][(w*16 + i*8)*64]);
    }
    #pragma unroll
    for (int i = 0; i < 2; ++i){
      int d = w*16 + i*8 + (l>>3);
      int cs = (l&7) ^ (d&7);
      gl2lds16(vtb + (size_t)d*SL + kg + cs*8, &Vbuf[cur][(w*16 + i*8)*64]);
    }
  };
  f32x4 acc[4] = {};
  float lsum = 0.f;
  int kbeg = s*(SL/FSPLIT);
  const int NIT = (SL/FSPLIT)/64;  // 16
  stage(0, kbeg);
  __syncthreads();
  for (int it = 0; it < NIT; ++it){
    int cur = it & 1;
    if (it + 1 < NIT) stage(cur^1, kbeg + (it+1)*64);
    int k0 = kbeg + it*64;
    float pv[4][4];
    #pragma unroll
    for (int t = 0; t < 4; ++t){
      int rb = (t*16 + lr)*64;
      short8 ka0 = *(const short8*)&Kbuf[cur][rb + ((  lg) ^ dx)*8];
      short8 ka1 = *(const short8*)&Kbuf[cur][rb + ((4+lg) ^ dx)*8];
      f32x4 sc = {};
      sc = mfma16(ka0, bq0, sc);
      sc = mfma16(ka1, bq1, sc);
      #pragma unroll
      for (int j = 0; j < 4; ++j) pv[t][j] = sc[j];
    }
    if (sel >= 0){
      #pragma unroll
      for (int t = 0; t < 4; ++t)
        #pragma unroll
        for (int j = 0; j < 4; ++j)
          pv[t][j] += mrow[k0 + t*16 + lg*4 + j];
    }
    #pragma unroll
    for (int t = 0; t < 4; ++t)
      #pragma unroll
      for (int j = 0; j < 4; ++j){
        float pp = exp2f(pv[t][j]);
        pv[t][j] = pp;
        lsum += pp;
      }
    short8 paf[2];
    #pragma unroll
    for (int kt = 0; kt < 2; ++kt){
      union { unsigned u[4]; short8 s8; } uu;
      uu.u[0] = cvtpk(pv[2*kt][0],   pv[2*kt][1]);
      uu.u[1] = cvtpk(pv[2*kt][2],   pv[2*kt][3]);
      uu.u[2] = cvtpk(pv[2*kt+1][0], pv[2*kt+1][1]);
      uu.u[3] = cvtpk(pv[2*kt+1][2], pv[2*kt+1][3]);
      paf[kt] = uu.s8;
    }
    #pragma unroll
    for (int c = 0; c < 4; ++c){
      const s16* vb = &Vbuf[cur][(c*16 + lr)*64];
      #pragma unroll
      for (int kt = 0; kt < 2; ++kt){
        short4_t lo = *(const short4_t*)&vb[((8*kt   + lg) ^ (dx<<1))*4];
        short4_t hi = *(const short4_t*)&vb[((8*kt+4 + lg) ^ (dx<<1))*4];
        short8 vf = __builtin_shufflevector(lo, hi, 0, 1, 2, 3, 4, 5, 6, 7);
        acc[c] = mfma16(vf, paf[kt], acc[c]);
      }
    }
    __syncthreads();
  }
  lsum += __shfl_xor(lsum, 16);
  lsum += __shfl_xor(lsum, 32);
  size_t row = (size_t)bh*SL + q0 + lr;
  float* Op = Opart + ((size_t)s*NROWS + row)*DH;
  #pragma unroll
  for (int c = 0; c < 4; ++c)
    *(f32x4*)(Op + c*16 + lg*4) = acc[c];
  if (lg == 0)
    lpart[(size_t)s*NROWS + row] = lsum;
}

// ---------- combine flash partials (no-max: plain sums) ----------
__global__ __launch_bounds__(256) void flash_combine(const float* __restrict__ Opart,
        const float* __restrict__ lpart, s16* __restrict__ outh){
  int row = blockIdx.x*4 + (threadIdx.x >> 6);
  int d = threadIdx.x & 63;
  float L = lpart[row] + lpart[NROWS + row];
  float o = (Opart[(size_t)row*DH + d] + Opart[((size_t)NROWS + row)*DH + d]) / L;
  int b = row >> 14, h = (row >> 11) & 7, q = row & (SL - 1);
  outh[((size_t)b*SL + q)*DM + h*DH + d] = f2bf(o);
}

extern "C" void kernel_launch(void* const* d_in, const int* in_sizes, int n_in,
                              void* d_out, int out_size, void* d_ws, size_t ws_size,
                              hipStream_t stream){
  (void)in_sizes; (void)n_in; (void)out_size;
  const float* query = (const float*)d_in[0];
  const float* key   = (const float*)d_in[1];
  const float* value = (const float*)d_in[2];
  const float* wq    = (const float*)d_in[3];
  const float* wk    = (const float*)d_in[4];
  const float* wv    = (const float*)d_in[5];
  const float* bq    = (const float*)d_in[6];
  const float* bk    = (const float*)d_in[7];
  const float* bv    = (const float*)d_in[8];
  const float* wo    = (const float*)d_in[9];
  const float* bo    = (const float*)d_in[10];

  const size_t NE = (size_t)NB*SL*DM;     // 2,097,152
  const size_t WE = (size_t)DM*DM;        // 262,144

  char* p = (char*)d_ws;
  size_t off = 0;
  auto alloc = [&](size_t n)->char*{ char* r = p + off; off += (n + 255) & ~(size_t)255; return r; };
  // --- long-lived ---
  s16* wob = (s16*)alloc(WE*2);
  s16* Qp  = (s16*)alloc(NE*2);
  s16* Kp  = (s16*)alloc(NE*2);
  s16* VpT = (s16*)alloc(NE*2);
  float* maskrows = (float*)alloc((size_t)NB*NH*NTOP*SL*4);
  int* topidx   = (int*)alloc((size_t)NB*NH*8*4);
  int* rowsel   = (int*)alloc((size_t)NROWS*4);
  float* Mmx    = (float*)alloc((size_t)SSPLIT*NROWS*4);
  float* Msm    = (float*)alloc((size_t)SSPLIT*NROWS*4);
  float* lpart  = (float*)alloc((size_t)FSPLIT*NROWS*4);
  s16* outh = (s16*)alloc(NE*2);
  // --- transients (dead before flash_kernel runs) ---
  size_t offA = off;
  s16* q_hi = (s16*)alloc(NE*2);
  s16* q_lo = (s16*)alloc(NE*2);
  s16* xk   = (s16*)alloc(NE*2);
  s16* xv   = (s16*)alloc(NE*2);
  s16* khatT_hi = (s16*)alloc(NE*2);
  s16* khatT_lo = (s16*)alloc(NE*2);
  s16* wqb = (s16*)alloc(WE*2);
  s16* wkb = (s16*)alloc(WE*2);
  s16* wvb = (s16*)alloc(WE*2);
  s16* Vp  = (s16*)alloc(NE*2);
  // Opart (16 MB) overlays the transient block (24+ MB) — lifetimes disjoint.
  float* Opart = (float*)(p + offA);
  size_t needOpart = offA + (size_t)FSPLIT*NROWS*DH*4;
  if (off > ws_size || needOpart > ws_size) return;

  const int nbb = (int)(NE/256);   // 8192
  const int wbb = (int)(WE/256);   // 1024
  prep_kernel<<<3*nbb + 512 + 4*wbb, 256, 0, stream>>>(query, key, value, wq, wk, wv, wo,
      q_hi, q_lo, xk, xv, khatT_hi, khatT_lo, wqb, wkb, wvb, wob);

  gemm_proj<<<3*256, 256, 0, stream>>>(q_hi, xk, xv, wqb, wkb, wvb, bq, bk, bv, Qp, Kp, Vp);
  vpt_kernel<<<512, 256, 0, stream>>>(Vp, VpT);

  stats_kernel<<<NB*NH*(SL/64)*SSPLIT, 256, 0, stream>>>(q_hi, q_lo, khatT_hi, khatT_lo, Mmx, Msm);
  topk_kernel<<<NB*NH, 64, 0, stream>>>(Mmx, Msm, topidx, rowsel);
  maskrow_kernel<<<512, 256, 0, stream>>>(query, key, topidx, maskrows);

  flash_kernel<<<NB*NH*(SL/64)*FSPLIT, 256, 0, stream>>>(Qp, Kp, VpT, maskrows, rowsel,
      Opart, lpart);
  flash_combine<<<NROWS/4, 256, 0, stream>>>(Opart, lpart, outh);
  gemm_out<<<256, 256, 0, stream>>>(outh, wob, bo, (float*)d_out);
}

// Round 7
// 139.858 us; speedup vs baseline: 1.1795x; 1.1795x over previous
//
#include <hip/hip_runtime.h>
#include <type_traits>

#define DEV static __device__ __forceinline__

typedef short s16;
typedef __attribute__((ext_vector_type(4))) short short4_t;
typedef __attribute__((ext_vector_type(8))) short short8;
typedef __attribute__((ext_vector_type(4))) float f32x4;

#define NB 2
#define NH 8
#define SL 2048
#define DM 512
#define DH 64
#define NTOP 7
#define LOG2E 1.4426950408889634f
#define NROWS (NB*NH*SL)      // 32768
#define FSPLIT 2
#define SSPLIT 2

DEV short f2bf(float x){
  union { float f; unsigned u; } v; v.f = x;
  unsigned r = v.u + 0x7fffu + ((v.u >> 16) & 1u);
  return (short)(r >> 16);
}
DEV float bf2f(short b){
  union { float f; unsigned u; } v; v.u = ((unsigned)(unsigned short)b) << 16;
  return v.f;
}
DEV f32x4 mfma16(short8 a, short8 b, f32x4 c){
  return __builtin_amdgcn_mfma_f32_16x16x32_bf16(a, b, c, 0, 0, 0);
}
DEV unsigned cvtpk(float lo, float hi){
  unsigned r;
  asm("v_cvt_pk_bf16_f32 %0, %1, %2" : "=v"(r) : "v"(lo), "v"(hi));
  return r;
}
// async global->LDS, 16B per lane; LDS dest = wave-uniform base + lane*16
DEV void gl2lds16(const s16* g, s16* l){
  __builtin_amdgcn_global_load_lds(
      (const __attribute__((address_space(1))) unsigned*)g,
      (__attribute__((address_space(3))) unsigned*)l, 16, 0, 0);
}

// ---------- fused prep: converts + tiled khatT transpose ----------
__global__ void prep_kernel(const float* __restrict__ query, const float* __restrict__ key,
    const float* __restrict__ value,
    const float* __restrict__ wq, const float* __restrict__ wk,
    const float* __restrict__ wv, const float* __restrict__ wo,
    s16* __restrict__ q_hi, s16* __restrict__ q_lo, s16* __restrict__ xk, s16* __restrict__ xv,
    s16* __restrict__ khi, s16* __restrict__ klo,
    s16* __restrict__ wqb, s16* __restrict__ wkb, s16* __restrict__ wvb, s16* __restrict__ wob){
  const int nbb = (NB*SL*DM)/256;   // 8192
  const int wbb = (DM*DM)/256;      // 1024
  __shared__ s16 thi[64][66];
  __shared__ s16 tlo[64][66];
  int bid = blockIdx.x;
  int t = threadIdx.x;
  if (bid < nbb){
    int i = bid*256 + t;
    float v = query[i];
    short h = f2bf(v);
    q_hi[i] = h;
    q_lo[i] = f2bf(v - bf2f(h));
    return;
  }
  bid -= nbb;
  if (bid < nbb){ int i = bid*256 + t; xk[i] = f2bf(key[i]); return; }
  bid -= nbb;
  if (bid < nbb){ int i = bid*256 + t; xv[i] = f2bf(value[i]); return; }
  bid -= nbb;
  if (bid < 512){
    // khatT[b][h][k][d] = key[b, d*32 + k/64, h*64 + k%64], tiled (b,h,k6)
    int k6 = bid & 31, h = (bid >> 5) & 7, b = bid >> 8;
    int kl = t & 63, dq = t >> 6;
    #pragma unroll
    for (int dd = 0; dd < 16; ++dd){
      int d = dd*4 + dq;
      float v = key[((size_t)b*SL + d*32 + k6)*DM + h*DH + kl];
      short hh = f2bf(v);
      thi[d][kl] = hh;
      tlo[d][kl] = f2bf(v - bf2f(hh));
    }
    __syncthreads();
    int d2 = t & 63, kq = t >> 6;
    size_t obase = (((size_t)(b*NH + h))*SL + (size_t)k6*64)*DH;
    #pragma unroll
    for (int kk = 0; kk < 16; ++kk){
      int kl2 = kk*4 + kq;
      khi[obase + (size_t)kl2*DH + d2] = thi[d2][kl2];
      klo[obase + (size_t)kl2*DH + d2] = tlo[d2][kl2];
    }
    return;
  }
  bid -= 512;
  if (bid < wbb){ int i = bid*256 + t; wqb[i] = f2bf(wq[i]); return; }
  bid -= wbb;
  if (bid < wbb){ int i = bid*256 + t; wkb[i] = f2bf(wk[i]); return; }
  bid -= wbb;
  if (bid < wbb){ int i = bid*256 + t; wvb[i] = f2bf(wv[i]); return; }
  bid -= wbb;
  if (bid < wbb){ int i = bid*256 + t; wob[i] = f2bf(wo[i]); return; }
}

// ---------- tiled transpose: VpT[b][h][d][k] = Vp[b][k][h*64+d] ----------
__global__ __launch_bounds__(256) void vpt_kernel(const s16* __restrict__ Vp, s16* __restrict__ VpT){
  __shared__ s16 tl[64][66];
  int bid = blockIdx.x;                 // (b,h,k6)
  int k6 = bid & 31, h = (bid >> 5) & 7, b = bid >> 8;
  int t = threadIdx.x;
  int d = t & 63, kq = t >> 6;
  #pragma unroll
  for (int kk = 0; kk < 16; ++kk){
    int kl = kk*4 + kq;
    tl[kl][d] = Vp[((size_t)b*SL + k6*64 + kl)*DM + h*DH + d];
  }
  __syncthreads();
  int kl2 = t & 63, dq = t >> 6;
  size_t obase = ((size_t)(b*NH + h))*DH*SL + (size_t)k6*64;
  #pragma unroll
  for (int dd = 0; dd < 16; ++dd){
    int d2 = dd*4 + dq;
    VpT[obase + (size_t)d2*SL + kl2] = tl[kl2][d2];
  }
}

// ---------- LDS-staged GEMM: C[n][o] = (sum_k A[n][k]*Bw[o][k] + bias[o])*scale ----------
template<int OUTF32>
DEV void gemm_body(const s16* __restrict__ A, const s16* __restrict__ Bw,
        const float* __restrict__ bias, void* __restrict__ Cout, int bid, int tid, float scale){
  __shared__ __align__(16) s16 Abuf[2][128*64];
  __shared__ __align__(16) s16 Bbuf[2][64*64];
  int nt = bid >> 3, ot = bid & 7;
  int w = tid >> 6, l = tid & 63;
  int lr = l & 15, lg = l >> 4;
  int n0 = nt*128, o0 = ot*64;
  auto stage = [&](int cur, int kg){
    #pragma unroll
    for (int i = 0; i < 4; ++i){
      int r = w*32 + i*8 + (l>>3);
      int cs = (l&7) ^ (r&7);
      gl2lds16(A + (size_t)(n0 + r)*DM + kg + cs*8, &Abuf[cur][(w*32 + i*8)*64]);
    }
    #pragma unroll
    for (int i = 0; i < 2; ++i){
      int r = w*16 + i*8 + (l>>3);
      int cs = (l&7) ^ (r&7);
      gl2lds16(Bw + (size_t)(o0 + r)*DM + kg + cs*8, &Bbuf[cur][(w*16 + i*8)*64]);
    }
  };
  f32x4 acc[2][4] = {};
  stage(0, 0);
  __syncthreads();
  const int NIT = DM/64;  // 8
  for (int it = 0; it < NIT; ++it){
    int cur = it & 1;
    if (it + 1 < NIT) stage(cur^1, (it+1)*64);
    #pragma unroll
    for (int kc = 0; kc < 2; ++kc){
      short8 a0 = *(const short8*)&Abuf[cur][(w*32 +      lr)*64 + ((kc*4+lg) ^ (lr&7))*8];
      short8 a1 = *(const short8*)&Abuf[cur][(w*32 + 16 + lr)*64 + ((kc*4+lg) ^ (lr&7))*8];
      #pragma unroll
      for (int c = 0; c < 4; ++c){
        short8 bf = *(const short8*)&Bbuf[cur][(c*16 + lr)*64 + ((kc*4+lg) ^ (lr&7))*8];
        acc[0][c] = mfma16(a0, bf, acc[0][c]);
        acc[1][c] = mfma16(a1, bf, acc[1][c]);
      }
    }
    __syncthreads();
  }
  #pragma unroll
  for (int sub = 0; sub < 2; ++sub)
    #pragma unroll
    for (int c = 0; c < 4; ++c){
      int col = o0 + c*16 + lr;
      float bb = bias[col];
      #pragma unroll
      for (int j = 0; j < 4; ++j){
        int row = n0 + w*32 + sub*16 + lg*4 + j;
        float v = (acc[sub][c][j] + bb)*scale;
        if (OUTF32) ((float*)Cout)[(size_t)row*DM + col] = v;
        else        ((s16*) Cout)[(size_t)row*DM + col] = f2bf(v);
      }
    }
}

__global__ __launch_bounds__(256) void gemm_proj(const s16* __restrict__ Aq, const s16* __restrict__ Ak,
        const s16* __restrict__ Av, const s16* __restrict__ Wq, const s16* __restrict__ Wk,
        const s16* __restrict__ Wv, const float* __restrict__ bq, const float* __restrict__ bk,
        const float* __restrict__ bv, s16* __restrict__ Oq, s16* __restrict__ Ok, s16* __restrict__ Ov){
  int which = blockIdx.x >> 8;
  const s16* A  = which == 0 ? Aq : which == 1 ? Ak : Av;
  const s16* Bw = which == 0 ? Wq : which == 1 ? Wk : Wv;
  const float* bias = which == 0 ? bq : which == 1 ? bk : bv;
  s16* C = which == 0 ? Oq : which == 1 ? Ok : Ov;
  float scale = which == 0 ? 0.125f*LOG2E : 1.0f;  // fold softmax scale+log2e into Q
  gemm_body<0>(A, Bw, bias, C, blockIdx.x & 255, threadIdx.x, scale);
}

__global__ __launch_bounds__(256) void gemm_out(const s16* __restrict__ A, const s16* __restrict__ Bw,
        const float* __restrict__ bias, float* __restrict__ Cout){
  gemm_body<1>(A, Bw, bias, Cout, blockIdx.x, threadIdx.x, 1.0f);
}

// ---------- stats partials: 8 waves, 128 q/block, hoisted LDS addrs, unroll-2 ----------
__global__ __launch_bounds__(512) void stats_kernel(const s16* __restrict__ qhi, const s16* __restrict__ qlo,
        const s16* __restrict__ khi, const s16* __restrict__ klo,
        float* __restrict__ Mmx, float* __restrict__ Msm){
  __shared__ __align__(16) s16 Hbuf[2][64*64];
  __shared__ __align__(16) s16 Lbuf[2][64*64];
  int bid = blockIdx.x;
  int s = bid & 1, qt = (bid >> 1) & 15, h = (bid >> 5) & 7, b = bid >> 8;
  int tid = threadIdx.x;
  int w = tid >> 6, l = tid & 63;
  int lr = l & 15, lg = l >> 4;
  int dx = lr & 7;
  int q0 = qt*128 + w*16;
  const s16* qp  = qhi + ((size_t)b*SL + q0 + lr)*DM + h*DH + lg*8;
  const s16* qlp = qlo + ((size_t)b*SL + q0 + lr)*DM + h*DH + lg*8;
  short8 qh0 = *(const short8*)qp;
  short8 qh1 = *(const short8*)(qp + 32);
  short8 ql0 = *(const short8*)qlp;
  short8 ql1 = *(const short8*)(qlp + 32);
  const s16* kb  = khi + ((size_t)b*NH + h)*SL*DH;
  const s16* klb = klo + ((size_t)b*NH + h)*SL*DH;
  // hoisted LDS read bases; Hbuf[1] = Hbuf[0] + 4096 elements
  const s16* hR0 = &Hbuf[0][lr*64 + ((lg      ^ dx)*8)];
  const s16* hR1 = &Hbuf[0][lr*64 + (((4+lg) ^ dx)*8)];
  const s16* lR0 = &Lbuf[0][lr*64 + ((lg      ^ dx)*8)];
  const s16* lR1 = &Lbuf[0][lr*64 + (((4+lg) ^ dx)*8)];
  int rS = tid >> 3;
  int csK = (tid & 7) ^ (rS & 7);
  auto stage = [&](int cur, int kg){
    gl2lds16(kb  + (size_t)(kg + rS)*DH + csK*8, &Hbuf[cur][w*512]);
    gl2lds16(klb + (size_t)(kg + rS)*DH + csK*8, &Lbuf[cur][w*512]);
  };
  float mx = -1e30f, sm = 0.f;
  auto body = [&](auto CURC){
    constexpr int CUR = decltype(CURC)::value;
    #pragma unroll
    for (int t = 0; t < 4; ++t){
      short8 kh0 = *(const short8*)(hR0 + CUR*4096 + t*1024);
      short8 kh1 = *(const short8*)(hR1 + CUR*4096 + t*1024);
      short8 kl0 = *(const short8*)(lR0 + CUR*4096 + t*1024);
      short8 kl1 = *(const short8*)(lR1 + CUR*4096 + t*1024);
      f32x4 sacc = {};
      sacc = mfma16(kh0, qh0, sacc);
      sacc = mfma16(kh1, qh1, sacc);
      sacc = mfma16(kl0, qh0, sacc);
      sacc = mfma16(kl1, qh1, sacc);
      sacc = mfma16(kh0, ql0, sacc);
      sacc = mfma16(kh1, ql1, sacc);
      #pragma unroll
      for (int j = 0; j < 4; ++j){ mx = fmaxf(mx, sacc[j]); sm += sacc[j]; }
    }
  };
  int kbeg = s*(SL/SSPLIT);
  stage(0, kbeg);
  __syncthreads();
  #pragma unroll 1
  for (int i2 = 0; i2 < 8; ++i2){
    stage(1, kbeg + (2*i2+1)*64);
    body(std::integral_constant<int,0>{});
    __syncthreads();
    if (i2 < 7) stage(0, kbeg + (2*i2+2)*64);
    body(std::integral_constant<int,1>{});
    __syncthreads();
  }
  mx = fmaxf(mx, __shfl_xor(mx, 16));
  mx = fmaxf(mx, __shfl_xor(mx, 32));
  sm += __shfl_xor(sm, 16);
  sm += __shfl_xor(sm, 32);
  if (lg == 0){
    size_t row = ((size_t)b*NH + h)*SL + q0 + lr;
    Mmx[(size_t)s*NROWS + row] = mx;
    Msm[(size_t)s*NROWS + row] = sm;
  }
}

// ---------- top-7 per (b,h), 256 threads, two-stage argmax ----------
__global__ __launch_bounds__(256) void topk_kernel(const float* __restrict__ Mmx,
        const float* __restrict__ Msm, int* __restrict__ topidx, int* __restrict__ rowsel){
  int bh = blockIdx.x;
  int t = threadIdx.x;
  int w = t >> 6, l = t & 63;
  __shared__ float smv[SL];
  __shared__ float rv[4];
  __shared__ int   ri[4];
  size_t base = (size_t)bh*SL;
  for (int i = t; i < SL; i += 256){
    float mx = Mmx[base + i];
    float sm = Msm[base + i];
    #pragma unroll
    for (int s = 1; s < SSPLIT; ++s){
      mx = fmaxf(mx, Mmx[(size_t)s*NROWS + base + i]);
      sm += Msm[(size_t)s*NROWS + base + i];
    }
    smv[i] = mx - sm*(1.0f/SL);
    rowsel[base + i] = -1;
  }
  __syncthreads();
  for (int tt = 0; tt < NTOP; ++tt){
    float bvv = -1e38f; int bi = SL;
    for (int i = t; i < SL; i += 256){
      float v = smv[i];
      if (v > bvv){ bvv = v; bi = i; }
    }
    #pragma unroll
    for (int off = 32; off >= 1; off >>= 1){
      float ov = __shfl_xor(bvv, off);
      int oi = __shfl_xor(bi, off);
      if (ov > bvv || (ov == bvv && oi < bi)){ bvv = ov; bi = oi; }
    }
    if (l == 0){ rv[w] = bvv; ri[w] = bi; }
    __syncthreads();
    if (t == 0){
      float bv2 = rv[0]; int bi2 = ri[0];
      #pragma unroll
      for (int ww = 1; ww < 4; ++ww)
        if (rv[ww] > bv2 || (rv[ww] == bv2 && ri[ww] < bi2)){ bv2 = rv[ww]; bi2 = ri[ww]; }
      topidx[bh*8 + tt] = bi2;
      rowsel[base + bi2] = tt;
      smv[bi2] = -1e38f;
    }
    __syncthreads();
  }
}

// ---------- mask rows (exact f32, LDS-tiled over (b,h,k6)), pre-scaled by LOG2E ----------
__global__ __launch_bounds__(256) void maskrow_kernel(const float* __restrict__ query,
        const float* __restrict__ key, const int* __restrict__ topidx, float* __restrict__ maskrows){
  __shared__ float tile[64][65];      // [d][kl]
  __shared__ float qs[NTOP][64];
  int bid = blockIdx.x;               // (b,h,k6)
  int k6 = bid & 31, h = (bid >> 5) & 7, b = bid >> 8;
  int bh = b*NH + h;
  int t = threadIdx.x;
  int kl = t & 63, w = t >> 6;
  for (int i = t; i < NTOP*64; i += 256){
    int tt = i >> 6, d = i & 63;
    qs[tt][d] = query[((size_t)b*SL + topidx[bh*8 + tt])*DM + h*DH + d];
  }
  #pragma unroll
  for (int dd = 0; dd < 16; ++dd){
    int d = dd*4 + w;
    tile[d][kl] = key[((size_t)b*SL + d*32 + k6)*DM + h*DH + kl];
  }
  __syncthreads();
  for (int tt = w; tt < NTOP; tt += 4){
    float acc = 0.f;
    #pragma unroll
    for (int d = 0; d < 64; ++d)
      acc = fmaf(qs[tt][d], tile[d][kl], acc);
    maskrows[((size_t)bh*NTOP + tt)*SL + k6*64 + kl] = acc*LOG2E;
  }
}

// ---------- flash attention: 8 waves, 128 q/block, KVBLK=64, no-max softmax ----------
// softmax without max-subtraction: |S*0.125*log2e| <= ~2 unmasked; masked rows add
// |QK_red|*log2e <= ~60 << 127 -> exp2 cannot overflow f32, shift-invariance exact.
__global__ __launch_bounds__(512) void flash_kernel(const s16* __restrict__ Qp, const s16* __restrict__ Kp,
        const s16* __restrict__ VpT, const float* __restrict__ maskrows, const int* __restrict__ rowsel,
        float* __restrict__ Opart, float* __restrict__ lpart){
  __shared__ __align__(16) s16 Kbuf[2][64*64];   // [k-row][64 d], swz 16B-chunk ^= (row&7)
  __shared__ __align__(16) s16 Vbuf[2][64*64];   // [d-row][64 k], swz as staged (8B-granule read)
  int bid = blockIdx.x;
  int s = bid & 1, qt = (bid >> 1) & 15, h = (bid >> 5) & 7, b = bid >> 8;
  int tid = threadIdx.x;
  int w = tid >> 6, l = tid & 63;
  int lr = l & 15, lg = l >> 4;
  int dx = lr & 7;
  int q0 = qt*128 + w*16;
  int bh = b*NH + h;
  const s16* qp = Qp + ((size_t)b*SL + q0 + lr)*DM + h*DH + lg*8;
  short8 bq0 = *(const short8*)qp;
  short8 bq1 = *(const short8*)(qp + 32);
  int sel = rowsel[(size_t)bh*SL + q0 + lr];
  const float* mrow = maskrows + ((size_t)bh*NTOP + (sel >= 0 ? sel : 0))*SL;
  const s16* kpb = Kp + (size_t)b*SL*DM + h*DH;
  const s16* vtb = VpT + (size_t)bh*DH*SL;
  // hoisted LDS read bases; buf[1] = buf[0] + 4096 elements
  const s16* kR0 = &Kbuf[0][lr*64 + ((lg      ^ dx)*8)];
  const s16* kR1 = &Kbuf[0][lr*64 + (((4+lg) ^ dx)*8)];
  const s16* vb0 = &Vbuf[0][lr*64];
  const int gL0 = ((0  + lg) ^ (dx<<1))*4;
  const int gH0 = ((4  + lg) ^ (dx<<1))*4;
  const int gL1 = ((8  + lg) ^ (dx<<1))*4;
  const int gH1 = ((12 + lg) ^ (dx<<1))*4;
  int rS = tid >> 3;
  int csK = (tid & 7) ^ (rS & 7);
  auto stage = [&](int cur, int kg){
    gl2lds16(kpb + (size_t)(kg + rS)*DM + csK*8, &Kbuf[cur][w*512]);
    gl2lds16(vtb + (size_t)rS*SL + kg + csK*8, &Vbuf[cur][w*512]);
  };
  f32x4 acc[4] = {};
  float lsum = 0.f;
  auto body = [&](auto CURC, int k0){
    constexpr int CUR = decltype(CURC)::value;
    float pv[4][4];
    #pragma unroll
    for (int t = 0; t < 4; ++t){
      short8 ka0 = *(const short8*)(kR0 + CUR*4096 + t*1024);
      short8 ka1 = *(const short8*)(kR1 + CUR*4096 + t*1024);
      f32x4 sc = {};
      sc = mfma16(ka0, bq0, sc);
      sc = mfma16(ka1, bq1, sc);
      #pragma unroll
      for (int j = 0; j < 4; ++j) pv[t][j] = sc[j];
    }
    if (sel >= 0){
      #pragma unroll
      for (int t = 0; t < 4; ++t)
        #pragma unroll
        for (int j = 0; j < 4; ++j)
          pv[t][j] += mrow[k0 + t*16 + lg*4 + j];
    }
    #pragma unroll
    for (int t = 0; t < 4; ++t)
      #pragma unroll
      for (int j = 0; j < 4; ++j){
        float pp = exp2f(pv[t][j]);
        pv[t][j] = pp;
        lsum += pp;
      }
    short8 paf[2];
    #pragma unroll
    for (int kt = 0; kt < 2; ++kt){
      union { unsigned u[4]; short8 s8; } uu;
      uu.u[0] = cvtpk(pv[2*kt][0],   pv[2*kt][1]);
      uu.u[1] = cvtpk(pv[2*kt][2],   pv[2*kt][3]);
      uu.u[2] = cvtpk(pv[2*kt+1][0], pv[2*kt+1][1]);
      uu.u[3] = cvtpk(pv[2*kt+1][2], pv[2*kt+1][3]);
      paf[kt] = uu.s8;
    }
    #pragma unroll
    for (int c = 0; c < 4; ++c){
      short4_t lo0 = *(const short4_t*)(vb0 + CUR*4096 + c*1024 + gL0);
      short4_t hi0 = *(const short4_t*)(vb0 + CUR*4096 + c*1024 + gH0);
      acc[c] = mfma16(__builtin_shufflevector(lo0, hi0, 0,1,2,3,4,5,6,7), paf[0], acc[c]);
      short4_t lo1 = *(const short4_t*)(vb0 + CUR*4096 + c*1024 + gL1);
      short4_t hi1 = *(const short4_t*)(vb0 + CUR*4096 + c*1024 + gH1);
      acc[c] = mfma16(__builtin_shufflevector(lo1, hi1, 0,1,2,3,4,5,6,7), paf[1], acc[c]);
    }
  };
  int kbeg = s*(SL/FSPLIT);
  stage(0, kbeg);
  __syncthreads();
  #pragma unroll 1
  for (int i2 = 0; i2 < 8; ++i2){
    stage(1, kbeg + (2*i2+1)*64);
    body(std::integral_constant<int,0>{}, kbeg + 2*i2*64);
    __syncthreads();
    if (i2 < 7) stage(0, kbeg + (2*i2+2)*64);
    body(std::integral_constant<int,1>{}, kbeg + (2*i2+1)*64);
    __syncthreads();
  }
  lsum += __shfl_xor(lsum, 16);
  lsum += __shfl_xor(lsum, 32);
  size_t row = (size_t)bh*SL + q0 + lr;
  float* Op = Opart + ((size_t)s*NROWS + row)*DH;
  #pragma unroll
  for (int c = 0; c < 4; ++c)
    *(f32x4*)(Op + c*16 + lg*4) = acc[c];
  if (lg == 0)
    lpart[(size_t)s*NROWS + row] = lsum;
}

// ---------- combine flash partials (no-max: plain sums) ----------
__global__ __launch_bounds__(256) void flash_combine(const float* __restrict__ Opart,
        const float* __restrict__ lpart, s16* __restrict__ outh){
  int row = blockIdx.x*4 + (threadIdx.x >> 6);
  int d = threadIdx.x & 63;
  float L = lpart[row] + lpart[NROWS + row];
  float o = (Opart[(size_t)row*DH + d] + Opart[((size_t)NROWS + row)*DH + d]) / L;
  int b = row >> 14, h = (row >> 11) & 7, q = row & (SL - 1);
  outh[((size_t)b*SL + q)*DM + h*DH + d] = f2bf(o);
}

extern "C" void kernel_launch(void* const* d_in, const int* in_sizes, int n_in,
                              void* d_out, int out_size, void* d_ws, size_t ws_size,
                              hipStream_t stream){
  (void)in_sizes; (void)n_in; (void)out_size;
  const float* query = (const float*)d_in[0];
  const float* key   = (const float*)d_in[1];
  const float* value = (const float*)d_in[2];
  const float* wq    = (const float*)d_in[3];
  const float* wk    = (const float*)d_in[4];
  const float* wv    = (const float*)d_in[5];
  const float* bq    = (const float*)d_in[6];
  const float* bk    = (const float*)d_in[7];
  const float* bv    = (const float*)d_in[8];
  const float* wo    = (const float*)d_in[9];
  const float* bo    = (const float*)d_in[10];

  const size_t NE = (size_t)NB*SL*DM;     // 2,097,152
  const size_t WE = (size_t)DM*DM;        // 262,144

  char* p = (char*)d_ws;
  size_t off = 0;
  auto alloc = [&](size_t n)->char*{ char* r = p + off; off += (n + 255) & ~(size_t)255; return r; };
  // --- long-lived ---
  s16* wob = (s16*)alloc(WE*2);
  s16* Qp  = (s16*)alloc(NE*2);
  s16* Kp  = (s16*)alloc(NE*2);
  s16* VpT = (s16*)alloc(NE*2);
  float* maskrows = (float*)alloc((size_t)NB*NH*NTOP*SL*4);
  int* topidx   = (int*)alloc((size_t)NB*NH*8*4);
  int* rowsel   = (int*)alloc((size_t)NROWS*4);
  float* Mmx    = (float*)alloc((size_t)SSPLIT*NROWS*4);
  float* Msm    = (float*)alloc((size_t)SSPLIT*NROWS*4);
  float* lpart  = (float*)alloc((size_t)FSPLIT*NROWS*4);
  s16* outh = (s16*)alloc(NE*2);
  // --- transients (dead before flash_kernel runs) ---
  size_t offA = off;
  s16* q_hi = (s16*)alloc(NE*2);
  s16* q_lo = (s16*)alloc(NE*2);
  s16* xk   = (s16*)alloc(NE*2);
  s16* xv   = (s16*)alloc(NE*2);
  s16* khatT_hi = (s16*)alloc(NE*2);
  s16* khatT_lo = (s16*)alloc(NE*2);
  s16* wqb = (s16*)alloc(WE*2);
  s16* wkb = (s16*)alloc(WE*2);
  s16* wvb = (s16*)alloc(WE*2);
  s16* Vp  = (s16*)alloc(NE*2);
  // Opart (16 MB) overlays the transient block (24+ MB) — lifetimes disjoint.
  float* Opart = (float*)(p + offA);
  size_t needOpart = offA + (size_t)FSPLIT*NROWS*DH*4;
  if (off > ws_size || needOpart > ws_size) return;

  const int nbb = (int)(NE/256);   // 8192
  const int wbb = (int)(WE/256);   // 1024
  prep_kernel<<<3*nbb + 512 + 4*wbb, 256, 0, stream>>>(query, key, value, wq, wk, wv, wo,
      q_hi, q_lo, xk, xv, khatT_hi, khatT_lo, wqb, wkb, wvb, wob);

  gemm_proj<<<3*256, 256, 0, stream>>>(q_hi, xk, xv, wqb, wkb, wvb, bq, bk, bv, Qp, Kp, Vp);
  vpt_kernel<<<512, 256, 0, stream>>>(Vp, VpT);

  stats_kernel<<<NB*NH*(SL/128)*SSPLIT, 512, 0, stream>>>(q_hi, q_lo, khatT_hi, khatT_lo, Mmx, Msm);
  topk_kernel<<<NB*NH, 256, 0, stream>>>(Mmx, Msm, topidx, rowsel);
  maskrow_kernel<<<512, 256, 0, stream>>>(query, key, topidx, maskrows);

  flash_kernel<<<NB*NH*(SL/128)*FSPLIT, 512, 0, stream>>>(Qp, Kp, VpT, maskrows, rowsel,
      Opart, lpart);
  flash_combine<<<NROWS/4, 256, 0, stream>>>(Opart, lpart, outh);
  gemm_out<<<256, 256, 0, stream>>>(outh, wob, bo, (float*)d_out);
}